// Round 3
// baseline (977.239 us; speedup 1.0000x reference)
//
#include <hip/hip_runtime.h>

#define HEADS 4
#define OUT_CH 32
#define HC 128      // HEADS*OUT_CH
#define INC 128     // IN_CH
#define CAP 48      // per-row edge slot capacity (Poisson(16) tail safe)
#define NB 8        // row buckets (== XCD count)
#define QCAP 32768  // per (xcd-slot, bucket) queue capacity (mean 25000, sd~150)

typedef __attribute__((ext_vector_type(8))) short bfrag;   // 8 bf16
typedef __attribute__((ext_vector_type(4))) float ffrag;   // 4 fp32 acc

union U16 { uint4 u; bfrag f; };

__device__ __forceinline__ unsigned short f2bf(float f) {
  unsigned int u = __float_as_uint(f);
  unsigned int r = (u + 0x7FFFu + ((u >> 16) & 1u)) >> 16;
  return (unsigned short)r;
}

// ---------------------------------------------------------------------------
// prep (grid-wide, replaces single-block prep + hipMemsetAsync):
//   blocks [0,16): Wb = bf16(W), 1 float4 per thread; block 0 also does ce.
//   blocks [16,...): zero cnt[N] and qcnt[64].
__global__ __launch_bounds__(256) void prep_kernel(
    const float* __restrict__ W, const float* __restrict__ lew,
    const float* __restrict__ att, unsigned short* __restrict__ Wb,
    float* __restrict__ ce, int* __restrict__ cnt, int* __restrict__ qcnt,
    int N) {
  int bid = blockIdx.x;
  int tid = threadIdx.x;
  if (bid < 16) {
    int i4 = bid * 256 + tid;  // 4096 float4 == 16384 floats
    float4 v = ((const float4*)W)[i4];
    ushort4 o;
    o.x = f2bf(v.x);
    o.y = f2bf(v.y);
    o.z = f2bf(v.z);
    o.w = f2bf(v.w);
    ((ushort4*)Wb)[i4] = o;
    if (bid == 0 && tid < HEADS) {
      float s = 0.f;
      for (int c = 0; c < OUT_CH; ++c)
        s += lew[tid * OUT_CH + c] * att[tid * 96 + 2 * OUT_CH + c];
      ce[tid] = s;
    }
  } else {
    int zi = (bid - 16) * 256 + tid;
    int stride = (gridDim.x - 16) * 256;
    for (int i = zi; i < N; i += stride) cnt[i] = 0;
    if (zi < 64) qcnt[zi] = 0;
  }
}

// ---------------------------------------------------------------------------
// Fused: blocks [0,G) = MFMA GEMM (xh = x@W^T, bf16 out, + si/sj epilogue);
// blocks [G,G+B) = edge-record routing into 64 dense queues.
// R2 evidence: direct 4B scatter into slots cost 102 MB of partial-line
// writebacks (WRITE_SIZE 124.5 MB vs ~48 logical) ~= 85-100 us. Stage A now
// appends 8B records to queue[(xcd_proxy, row_bucket)] with wave-ballot
// aggregation: 1 atomic/wave/bucket, lanes store CONSECUTIVE records ->
// full-line writes (16.8 MB total). The real scatter happens in
// scatter_kernel with XCD-local L2 residency.
#define APITCH 136  // ushort pitch for 128-k row: ds_read_b128 <=2-way free
__global__ __launch_bounds__(256) void gemm_build(
    const float* __restrict__ x, const unsigned short* __restrict__ Wb,
    const float* __restrict__ att, const int* __restrict__ ei,
    const float* __restrict__ ea, unsigned short* __restrict__ xhb,
    float* __restrict__ si, float* __restrict__ sj, int* __restrict__ qcnt,
    unsigned long long* __restrict__ queue, int nrows, int E, int G,
    int bsz) {
  __shared__ unsigned short Als[4][16 * APITCH];  // 17408 B

  if (blockIdx.x >= G) {
    // ---- stage A: route edge records into dense per-(xcd,bucket) queues ----
    int e = (blockIdx.x - G) * 256 + threadIdx.x;
    int lane = threadIdx.x & 63;
    bool valid = e < E;
    int b = -1;
    unsigned long long rec = 0;
    if (valid) {
      int r = ei[e];
      int c = ei[E + e];
      unsigned int u = __float_as_uint(ea[e]);
      unsigned int word = ((u + 0x10000u) & 0xFFFE0000u) | (unsigned int)c;
      rec = ((unsigned long long)word << 32) | (unsigned int)r;
      b = r / bsz;
      if (b > NB - 1) b = NB - 1;
    }
    int xs = blockIdx.x & 7;  // XCD proxy (round-robin dispatch)
#pragma unroll
    for (int bb = 0; bb < NB; ++bb) {
      unsigned long long mask = __ballot(valid && (b == bb));
      if (mask == 0) continue;
      int nsel = __popcll(mask);
      int leader = __ffsll((unsigned long long)mask) - 1;
      int base = 0;
      if (lane == leader) base = atomicAdd(&qcnt[xs * NB + bb], nsel);
      base = __shfl(base, leader);
      if (valid && b == bb) {
        int rank = __popcll(mask & ((1ull << lane) - 1ull));
        int pos = base + rank;
        if (pos < QCAP)
          queue[((size_t)(xs * NB + bb) << 15) + pos] = rec;
      }
    }
    return;
  }

  // ---- MFMA GEMM branch: each wave owns 16 rows ----
  const int tid = threadIdx.x;
  const int wid = tid >> 6;
  const int lane = tid & 63;
  const int row0 = blockIdx.x * 64 + wid * 16;
  if (row0 >= nrows) return;
  unsigned short* As = &Als[wid][0];

  // stage 16 rows x 128 k: fp32 -> bf16 into private LDS strip (no barrier)
#pragma unroll
  for (int t = 0; t < 8; t++) {
    int idx = t * 64 + lane;        // 512 float4 total
    int r = idx >> 5;               // 32 float4 per row
    int q = idx & 31;
    int gr = row0 + r;
    float4 v = make_float4(0.f, 0.f, 0.f, 0.f);
    if (gr < nrows) v = ((const float4*)x)[(size_t)gr * 32 + q];
    unsigned int p0 = ((unsigned int)f2bf(v.y) << 16) | f2bf(v.x);
    unsigned int p1 = ((unsigned int)f2bf(v.w) << 16) | f2bf(v.z);
    *(uint2*)&As[r * APITCH + q * 4] = make_uint2(p0, p1);
  }

  const int m15 = lane & 15;
  const int g = lane >> 4;

  ffrag acc[8];
#pragma unroll
  for (int t = 0; t < 8; t++) acc[t] = (ffrag){0.f, 0.f, 0.f, 0.f};

#pragma unroll
  for (int ks = 0; ks < 4; ks++) {
    U16 a;
    a.u = *(const uint4*)&As[m15 * APITCH + ks * 32 + g * 8];
#pragma unroll
    for (int nt = 0; nt < 8; nt++) {
      U16 bfr;
      bfr.u = *(const uint4*)&Wb[(size_t)(nt * 16 + m15) * 128 + ks * 32 + g * 8];
      acc[nt] = __builtin_amdgcn_mfma_f32_16x16x32_bf16(a.f, bfr.f, acc[nt],
                                                        0, 0, 0);
    }
  }

  // ---- si/sj epilogue (C layout: col=lane&15 -> n, row=(lane>>4)*4+reg) ----
  float ai[8], aj[8];
#pragma unroll
  for (int t = 0; t < 8; t++) {
    int h = t >> 1, c = (t & 1) * 16 + m15;
    ai[t] = att[h * 96 + c];
    aj[t] = att[h * 96 + 32 + c];
  }
#pragma unroll
  for (int reg = 0; reg < 4; reg++) {
    float ph_i[4], ph_j[4];
#pragma unroll
    for (int h = 0; h < 4; h++) {
      ph_i[h] = acc[2 * h][reg] * ai[2 * h] + acc[2 * h + 1][reg] * ai[2 * h + 1];
      ph_j[h] = acc[2 * h][reg] * aj[2 * h] + acc[2 * h + 1][reg] * aj[2 * h + 1];
    }
#pragma unroll
    for (int off = 8; off >= 1; off >>= 1) {
#pragma unroll
      for (int h = 0; h < 4; h++) {
        ph_i[h] += __shfl_down(ph_i[h], off, 16);
        ph_j[h] += __shfl_down(ph_j[h], off, 16);
      }
    }
    int gr = row0 + g * 4 + reg;
    if (m15 == 0 && gr < nrows) {
#pragma unroll
      for (int h = 0; h < 4; h++) {
        si[(size_t)gr * 4 + h] = ph_i[h];
        sj[(size_t)gr * 4 + h] = ph_j[h];
      }
    }
  }

  // ---- bf16 repack via private LDS strip (pitch 128), coalesced store ----
#pragma unroll
  for (int t = 0; t < 8; t++) {
#pragma unroll
    for (int reg = 0; reg < 4; reg++) {
      int r = g * 4 + reg;
      int n = t * 16 + m15;
      As[r * 128 + n] = f2bf(acc[t][reg]);
    }
  }
  const uint4* src = (const uint4*)As;
#pragma unroll
  for (int t = 0; t < 4; t++) {
    int idx = t * 64 + lane;        // 256 uint4, 16 per row
    int r = idx >> 4, q = idx & 15;
    int gr = row0 + r;
    if (gr < nrows) ((uint4*)(xhb + (size_t)gr * 128))[q] = src[idx];
  }
}

// ---------------------------------------------------------------------------
// Stage B: drain the 8 queues of bucket b = blockIdx&7 (-> XCD b under
// round-robin dispatch). All rows in bucket b live in a 12500-row slice:
// slots slice = 2.4 MB < 4 MB XCD-L2, so scattered lines stay L2-resident
// until fully populated -> full-line writebacks instead of 64B-per-4B.
// cnt atomics are L2-local too. If the blockIdx->XCD mapping assumption is
// wrong, this degrades to current perf, never to incorrectness.
__global__ __launch_bounds__(256) void scatter_kernel(
    const unsigned long long* __restrict__ queue, const int* __restrict__ qcnt,
    int* __restrict__ cnt, unsigned int* __restrict__ slots) {
  int b = blockIdx.x & 7;
  int chunk = blockIdx.x >> 3;
  int nchunk = gridDim.x >> 3;
#pragma unroll
  for (int xs = 0; xs < NB; ++xs) {
    int qi = xs * NB + b;
    int m = qcnt[qi];
    if (m > QCAP) m = QCAP;
    const unsigned long long* q = queue + ((size_t)qi << 15);
    for (int i = chunk * 256 + threadIdx.x; i < m; i += nchunk * 256) {
      unsigned long long rec = q[i];
      int r = (int)(unsigned int)rec;
      unsigned int word = (unsigned int)(rec >> 32);
      int pos = atomicAdd(&cnt[r], 1);
      if (pos < CAP) slots[(size_t)r * CAP + pos] = word;
    }
  }
}

// ---------------------------------------------------------------------------
// Gather v2 (unchanged): one wave per destination node, two phases,
// LDS-broadcast of per-edge weights, pipelined coalesced xhb row gathers.
__global__ __launch_bounds__(256) void gather_kernel(
    const int* __restrict__ cnt, const unsigned int* __restrict__ slots,
    const float* __restrict__ si, const float* __restrict__ sj,
    const float* __restrict__ ce, const unsigned short* __restrict__ xhb,
    float* __restrict__ out, int n) {
  __shared__ int cls[4][CAP];        // per-wave column lists
  __shared__ float wls[4][4][CAP];   // per-wave [head][edge] weights

  int wid = threadIdx.x >> 6;
  int node = blockIdx.x * 4 + wid;
  if (node >= n) return;
  int lane = threadIdx.x & 63;
  int h = lane >> 4;

  int m = cnt[node];
  if (m > CAP) m = CAP;

  float4 si4 = *(const float4*)(si + (size_t)node * 4);
  float4 ce4 = *(const float4*)ce;

  // ---- phase 1: per-lane edge weights -> LDS ----
  if (lane < CAP) {
    int c = 0;
    float w0 = 0.f, w1 = 0.f, w2 = 0.f, w3 = 0.f;
    if (lane < m) {
      unsigned int word = slots[(size_t)node * CAP + lane];
      c = word & 0x1FFFF;
      float eaf = __uint_as_float(word & 0xFFFE0000u);
      float4 sjv = *(const float4*)(sj + (size_t)c * 4);
      float t0 = si4.x + sjv.x + eaf * ce4.x;
      float t1 = si4.y + sjv.y + eaf * ce4.y;
      float t2 = si4.z + sjv.z + eaf * ce4.z;
      float t3 = si4.w + sjv.w + eaf * ce4.w;
      t0 = t0 > 0.f ? t0 : 0.2f * t0;
      t1 = t1 > 0.f ? t1 : 0.2f * t1;
      t2 = t2 > 0.f ? t2 : 0.2f * t2;
      t3 = t3 > 0.f ? t3 : 0.2f * t3;
      w0 = __expf(t0);
      w1 = __expf(t1);
      w2 = __expf(t2);
      w3 = __expf(t3);
    }
    cls[wid][lane] = c;
    wls[wid][0][lane] = w0;
    wls[wid][1][lane] = w1;
    wls[wid][2][lane] = w2;
    wls[wid][3][lane] = w3;
  }
  // same-wave LDS dependency: compiler-inserted lgkmcnt orders write->read.

  // ---- phase 2: pipelined xhb row gathers ----
  const unsigned short* xb = xhb + lane * 2;  // lane -> channels 2l,2l+1
  float acc0 = 0.f, acc1 = 0.f, wsum = 0.f;
  for (int k = 0; k < m; k += 4) {
    int4 cc = *(const int4*)&cls[wid][k];
    float4 wv = *(const float4*)&wls[wid][h][k];
    unsigned int x0 = *(const unsigned int*)(xb + (size_t)cc.x * 128);
    unsigned int x1 = *(const unsigned int*)(xb + (size_t)cc.y * 128);
    unsigned int x2 = *(const unsigned int*)(xb + (size_t)cc.z * 128);
    unsigned int x3 = *(const unsigned int*)(xb + (size_t)cc.w * 128);
    acc0 += wv.x * __uint_as_float(x0 << 16) +
            wv.y * __uint_as_float(x1 << 16) +
            wv.z * __uint_as_float(x2 << 16) +
            wv.w * __uint_as_float(x3 << 16);
    acc1 += wv.x * __uint_as_float(x0 & 0xFFFF0000u) +
            wv.y * __uint_as_float(x1 & 0xFFFF0000u) +
            wv.z * __uint_as_float(x2 & 0xFFFF0000u) +
            wv.w * __uint_as_float(x3 & 0xFFFF0000u);
    wsum += wv.x + wv.y + wv.z + wv.w;
  }

  float inv = 1.0f / (wsum + 1e-16f);
  float2 o;
  o.x = acc0 * inv;
  o.y = acc1 * inv;
  *(float2*)(out + (size_t)node * HC + lane * 2) = o;
}

// ---------------------------------------------------------------------------
extern "C" void kernel_launch(void* const* d_in, const int* in_sizes, int n_in,
                              void* d_out, int out_size, void* d_ws,
                              size_t ws_size, hipStream_t stream) {
  const float* x = (const float*)d_in[0];
  const float* edge_attr = (const float*)d_in[1];
  const int* ei = (const int*)d_in[2];
  const float* lin_w = (const float*)d_in[3];
  const float* lew = (const float*)d_in[4];
  const float* att = (const float*)d_in[5];
  float* out = (float*)d_out;

  const int N = in_sizes[0] / INC;
  const int E = in_sizes[1];

  // workspace layout (4-byte units; all segments 16 B aligned)
  unsigned int* slots = (unsigned int*)d_ws;                         // N*CAP
  unsigned short* xhb = (unsigned short*)(slots + (size_t)N * CAP);  // N*128
  float* si = (float*)(xhb + (size_t)N * 128);                       // N*4
  float* sj = si + (size_t)N * 4;                                    // N*4
  float* ce = sj + (size_t)N * 4;                                    // 16
  unsigned short* Wb = (unsigned short*)(ce + 16);                   // 16384
  int* cnt = (int*)(Wb + 16384);                                     // N
  int* qcnt = cnt + N;                                               // 64
  // queue scratch lives in d_out (16.8 MB <= 51.2 MB); consumed by
  // scatter_kernel strictly before gather overwrites out. Safe each launch.
  unsigned long long* queue = (unsigned long long*)d_out;

  const int bsz = (N + NB - 1) / NB;

  prep_kernel<<<128, 256, 0, stream>>>(lin_w, lew, att, Wb, ce, cnt, qcnt, N);

  const int G = (N + 63) / 64;       // gemm blocks (4 waves x 16 rows)
  const int B = (E + 255) / 256;     // build blocks
  gemm_build<<<G + B, 256, 0, stream>>>(x, Wb, att, ei, edge_attr, xhb, si,
                                        sj, qcnt, queue, N, E, G, bsz);
  scatter_kernel<<<2048, 256, 0, stream>>>(queue, qcnt, cnt, slots);
  gather_kernel<<<(N + 3) / 4, 256, 0, stream>>>(cnt, slots, si, sj, ce, xhb,
                                                 out, N);
}

// Round 4
// 278.795 us; speedup vs baseline: 3.5052x; 3.5052x over previous
//
#include <hip/hip_runtime.h>

#define HEADS 4
#define OUT_CH 32
#define HC 128      // HEADS*OUT_CH
#define INC 128     // IN_CH
#define CAP 48      // per-row edge slot capacity (Poisson(16) tail safe)

typedef __attribute__((ext_vector_type(8))) short bfrag;   // 8 bf16
typedef __attribute__((ext_vector_type(4))) float ffrag;   // 4 fp32 acc

union U16 { uint4 u; bfrag f; };

__device__ __forceinline__ unsigned short f2bf(float f) {
  unsigned int u = __float_as_uint(f);
  unsigned int r = (u + 0x7FFFu + ((u >> 16) & 1u)) >> 16;
  return (unsigned short)r;
}

// ---------------------------------------------------------------------------
// prep (grid-wide, replaces single-block prep + hipMemsetAsync):
//   blocks [0,16): Wb = bf16(W), 1 float4 per thread; block 0 also does ce.
//   blocks [16,...): zero cnt[N].
__global__ __launch_bounds__(256) void prep_kernel(
    const float* __restrict__ W, const float* __restrict__ lew,
    const float* __restrict__ att, unsigned short* __restrict__ Wb,
    float* __restrict__ ce, int* __restrict__ cnt, int N) {
  int bid = blockIdx.x;
  int tid = threadIdx.x;
  if (bid < 16) {
    int i4 = bid * 256 + tid;  // 4096 float4 == 16384 floats
    float4 v = ((const float4*)W)[i4];
    ushort4 o;
    o.x = f2bf(v.x);
    o.y = f2bf(v.y);
    o.z = f2bf(v.z);
    o.w = f2bf(v.w);
    ((ushort4*)Wb)[i4] = o;
    if (bid == 0 && tid < HEADS) {
      float s = 0.f;
      for (int c = 0; c < OUT_CH; ++c)
        s += lew[tid * OUT_CH + c] * att[tid * 96 + 2 * OUT_CH + c];
      ce[tid] = s;
    }
  } else {
    int zi = (bid - 16) * 256 + tid;
    int stride = (gridDim.x - 16) * 256;
    for (int i = zi; i < N; i += stride) cnt[i] = 0;
  }
}

// ---------------------------------------------------------------------------
// Fused: blocks [0,G) = MFMA GEMM (xh = x@W^T, bf16 out, + si/sj epilogue);
// blocks [G,G+B) = edge-table atomic-append build. R2-PROVEN FORM.
// R3 lesson: queue-based scatter with 64 shared counters = 3125 serialized
// atomics/counter = 735 us. Direct scatter's 1.6M atomics over 100K counters
// have no contention; its 102 MB partial-line writeback (~60-80 us) is the
// accepted cost until a contention-free dense route exists.
#define APITCH 136  // ushort pitch for 128-k row: ds_read_b128 <=2-way free
__global__ __launch_bounds__(256) void gemm_build(
    const float* __restrict__ x, const unsigned short* __restrict__ Wb,
    const float* __restrict__ att, const int* __restrict__ ei,
    const float* __restrict__ ea, unsigned short* __restrict__ xhb,
    float* __restrict__ si, float* __restrict__ sj, int* __restrict__ cnt,
    unsigned int* __restrict__ slots, int nrows, int E, int G) {
  __shared__ unsigned short Als[4][16 * APITCH];  // 17408 B

  if (blockIdx.x >= G) {
    // ---- edge-table build branch ----
    int e = (blockIdx.x - G) * 256 + threadIdx.x;
    if (e < E) {
      int r = ei[e];
      int c = ei[E + e];
      unsigned int u = __float_as_uint(ea[e]);
      unsigned int word = ((u + 0x10000u) & 0xFFFE0000u) | (unsigned int)c;
      int pos = atomicAdd(&cnt[r], 1);
      if (pos < CAP) slots[(size_t)r * CAP + pos] = word;
    }
    return;
  }

  // ---- MFMA GEMM branch: each wave owns 16 rows ----
  const int tid = threadIdx.x;
  const int wid = tid >> 6;
  const int lane = tid & 63;
  const int row0 = blockIdx.x * 64 + wid * 16;
  if (row0 >= nrows) return;
  unsigned short* As = &Als[wid][0];

  // stage 16 rows x 128 k: fp32 -> bf16 into private LDS strip (no barrier)
#pragma unroll
  for (int t = 0; t < 8; t++) {
    int idx = t * 64 + lane;        // 512 float4 total
    int r = idx >> 5;               // 32 float4 per row
    int q = idx & 31;
    int gr = row0 + r;
    float4 v = make_float4(0.f, 0.f, 0.f, 0.f);
    if (gr < nrows) v = ((const float4*)x)[(size_t)gr * 32 + q];
    unsigned int p0 = ((unsigned int)f2bf(v.y) << 16) | f2bf(v.x);
    unsigned int p1 = ((unsigned int)f2bf(v.w) << 16) | f2bf(v.z);
    *(uint2*)&As[r * APITCH + q * 4] = make_uint2(p0, p1);
  }

  const int m15 = lane & 15;
  const int g = lane >> 4;

  ffrag acc[8];
#pragma unroll
  for (int t = 0; t < 8; t++) acc[t] = (ffrag){0.f, 0.f, 0.f, 0.f};

#pragma unroll
  for (int ks = 0; ks < 4; ks++) {
    U16 a;
    a.u = *(const uint4*)&As[m15 * APITCH + ks * 32 + g * 8];
#pragma unroll
    for (int nt = 0; nt < 8; nt++) {
      U16 b;
      b.u = *(const uint4*)&Wb[(size_t)(nt * 16 + m15) * 128 + ks * 32 + g * 8];
      acc[nt] = __builtin_amdgcn_mfma_f32_16x16x32_bf16(a.f, b.f, acc[nt],
                                                        0, 0, 0);
    }
  }

  // ---- si/sj epilogue (C layout: col=lane&15 -> n, row=(lane>>4)*4+reg) ----
  float ai[8], aj[8];
#pragma unroll
  for (int t = 0; t < 8; t++) {
    int h = t >> 1, c = (t & 1) * 16 + m15;
    ai[t] = att[h * 96 + c];
    aj[t] = att[h * 96 + 32 + c];
  }
#pragma unroll
  for (int reg = 0; reg < 4; reg++) {
    float ph_i[4], ph_j[4];
#pragma unroll
    for (int h = 0; h < 4; h++) {
      ph_i[h] = acc[2 * h][reg] * ai[2 * h] + acc[2 * h + 1][reg] * ai[2 * h + 1];
      ph_j[h] = acc[2 * h][reg] * aj[2 * h] + acc[2 * h + 1][reg] * aj[2 * h + 1];
    }
#pragma unroll
    for (int off = 8; off >= 1; off >>= 1) {
#pragma unroll
      for (int h = 0; h < 4; h++) {
        ph_i[h] += __shfl_down(ph_i[h], off, 16);
        ph_j[h] += __shfl_down(ph_j[h], off, 16);
      }
    }
    int gr = row0 + g * 4 + reg;
    if (m15 == 0 && gr < nrows) {
#pragma unroll
      for (int h = 0; h < 4; h++) {
        si[(size_t)gr * 4 + h] = ph_i[h];
        sj[(size_t)gr * 4 + h] = ph_j[h];
      }
    }
  }

  // ---- bf16 repack via private LDS strip (pitch 128), coalesced store ----
#pragma unroll
  for (int t = 0; t < 8; t++) {
#pragma unroll
    for (int reg = 0; reg < 4; reg++) {
      int r = g * 4 + reg;
      int n = t * 16 + m15;
      As[r * 128 + n] = f2bf(acc[t][reg]);
    }
  }
  const uint4* src = (const uint4*)As;
#pragma unroll
  for (int t = 0; t < 4; t++) {
    int idx = t * 64 + lane;        // 256 uint4, 16 per row
    int r = idx >> 4, q = idx & 15;
    int gr = row0 + r;
    if (gr < nrows) ((uint4*)(xhb + (size_t)gr * 128))[q] = src[idx];
  }
}

// ---------------------------------------------------------------------------
// Gather v3: latency-chain-shortened version of v2 (R2, ~105 us).
// Cycle model said v2 was latency-bound: serial prelude (slot->sj->exp->LDS
// ~1000cy) + mean-4 phase-2 rounds each gated on ~700cy L3 round trip.
// Changes:
//  (a) de-gated prelude: slot word loaded unconditionally for lane<CAP
//      (always in-bounds), c clamped to [0,n) (garbage slots beyond cnt[] may
//      hold stale bits), sj gather issues immediately and no longer waits on
//      the cnt load; lane<m gate moved to the weight select (NaN-safe).
//  (b) phase 2 unrolled x8: 8 xhb row loads in flight per round -> half the
//      latency-exposed rounds. Padding weights are 0 so rounding m up to a
//      multiple of 8 (<=CAP) is free and tail-less.
__global__ __launch_bounds__(256) void gather_kernel(
    const int* __restrict__ cnt, const unsigned int* __restrict__ slots,
    const float* __restrict__ si, const float* __restrict__ sj,
    const float* __restrict__ ce, const unsigned short* __restrict__ xhb,
    float* __restrict__ out, int n) {
  __shared__ int cls[4][CAP];        // per-wave column lists
  __shared__ float wls[4][4][CAP];   // per-wave [head][edge] weights

  int wid = threadIdx.x >> 6;
  int node = blockIdx.x * 4 + wid;
  if (node >= n) return;
  int lane = threadIdx.x & 63;
  int h = lane >> 4;

  // issue independent loads up front (cnt, si, slot word all in parallel)
  int m = cnt[node];
  float4 si4 = *(const float4*)(si + (size_t)node * 4);
  float4 ce4 = *(const float4*)ce;

  if (lane < CAP) {
    unsigned int word = slots[(size_t)node * CAP + lane];
    int c = word & 0x1FFFF;
    if (c >= n) c = 0;  // stale-slot clamp; weight is zeroed below anyway
    float eaf = __uint_as_float(word & 0xFFFE0000u);
    float4 sjv = *(const float4*)(sj + (size_t)c * 4);
    float t0 = si4.x + sjv.x + eaf * ce4.x;
    float t1 = si4.y + sjv.y + eaf * ce4.y;
    float t2 = si4.z + sjv.z + eaf * ce4.z;
    float t3 = si4.w + sjv.w + eaf * ce4.w;
    t0 = t0 > 0.f ? t0 : 0.2f * t0;
    t1 = t1 > 0.f ? t1 : 0.2f * t1;
    t2 = t2 > 0.f ? t2 : 0.2f * t2;
    t3 = t3 > 0.f ? t3 : 0.2f * t3;
    bool live = lane < m;   // m <= CAP slots actually written this launch
    cls[wid][lane] = live ? c : 0;
    wls[wid][0][lane] = live ? __expf(t0) : 0.f;
    wls[wid][1][lane] = live ? __expf(t1) : 0.f;
    wls[wid][2][lane] = live ? __expf(t2) : 0.f;
    wls[wid][3][lane] = live ? __expf(t3) : 0.f;
  }
  if (m > CAP) m = CAP;
  int mr = (m + 7) & ~7;  // <= CAP; padding entries carry w=0
  // same-wave LDS dependency: compiler-inserted lgkmcnt orders write->read.

  // ---- phase 2: 8-deep pipelined xhb row gathers ----
  const unsigned short* xb = xhb + lane * 2;  // lane -> channels 2l,2l+1
  float acc0 = 0.f, acc1 = 0.f, wsum = 0.f;
  for (int k = 0; k < mr; k += 8) {
    int4 ca = *(const int4*)&cls[wid][k];
    int4 cb = *(const int4*)&cls[wid][k + 4];
    float4 wa = *(const float4*)&wls[wid][h][k];
    float4 wb = *(const float4*)&wls[wid][h][k + 4];
    unsigned int x0 = *(const unsigned int*)(xb + (size_t)ca.x * 128);
    unsigned int x1 = *(const unsigned int*)(xb + (size_t)ca.y * 128);
    unsigned int x2 = *(const unsigned int*)(xb + (size_t)ca.z * 128);
    unsigned int x3 = *(const unsigned int*)(xb + (size_t)ca.w * 128);
    unsigned int x4 = *(const unsigned int*)(xb + (size_t)cb.x * 128);
    unsigned int x5 = *(const unsigned int*)(xb + (size_t)cb.y * 128);
    unsigned int x6 = *(const unsigned int*)(xb + (size_t)cb.z * 128);
    unsigned int x7 = *(const unsigned int*)(xb + (size_t)cb.w * 128);
    acc0 += wa.x * __uint_as_float(x0 << 16) +
            wa.y * __uint_as_float(x1 << 16) +
            wa.z * __uint_as_float(x2 << 16) +
            wa.w * __uint_as_float(x3 << 16) +
            wb.x * __uint_as_float(x4 << 16) +
            wb.y * __uint_as_float(x5 << 16) +
            wb.z * __uint_as_float(x6 << 16) +
            wb.w * __uint_as_float(x7 << 16);
    acc1 += wa.x * __uint_as_float(x0 & 0xFFFF0000u) +
            wa.y * __uint_as_float(x1 & 0xFFFF0000u) +
            wa.z * __uint_as_float(x2 & 0xFFFF0000u) +
            wa.w * __uint_as_float(x3 & 0xFFFF0000u) +
            wb.x * __uint_as_float(x4 & 0xFFFF0000u) +
            wb.y * __uint_as_float(x5 & 0xFFFF0000u) +
            wb.z * __uint_as_float(x6 & 0xFFFF0000u) +
            wb.w * __uint_as_float(x7 & 0xFFFF0000u);
    wsum += wa.x + wa.y + wa.z + wa.w + wb.x + wb.y + wb.z + wb.w;
  }

  float inv = 1.0f / (wsum + 1e-16f);
  float2 o;
  o.x = acc0 * inv;
  o.y = acc1 * inv;
  *(float2*)(out + (size_t)node * HC + lane * 2) = o;
}

// ---------------------------------------------------------------------------
extern "C" void kernel_launch(void* const* d_in, const int* in_sizes, int n_in,
                              void* d_out, int out_size, void* d_ws,
                              size_t ws_size, hipStream_t stream) {
  const float* x = (const float*)d_in[0];
  const float* edge_attr = (const float*)d_in[1];
  const int* ei = (const int*)d_in[2];
  const float* lin_w = (const float*)d_in[3];
  const float* lew = (const float*)d_in[4];
  const float* att = (const float*)d_in[5];
  float* out = (float*)d_out;

  const int N = in_sizes[0] / INC;
  const int E = in_sizes[1];

  // workspace layout (4-byte units; all segments 16 B aligned)
  unsigned int* slots = (unsigned int*)d_ws;                         // N*CAP
  unsigned short* xhb = (unsigned short*)(slots + (size_t)N * CAP);  // N*128
  float* si = (float*)(xhb + (size_t)N * 128);                       // N*4
  float* sj = si + (size_t)N * 4;                                    // N*4
  float* ce = sj + (size_t)N * 4;                                    // 16
  unsigned short* Wb = (unsigned short*)(ce + 16);                   // 16384
  int* cnt = (int*)(Wb + 16384);                                     // N

  prep_kernel<<<128, 256, 0, stream>>>(lin_w, lew, att, Wb, ce, cnt, N);

  const int G = (N + 63) / 64;       // gemm blocks (4 waves x 16 rows)
  const int B = (E + 255) / 256;     // build blocks
  gemm_build<<<G + B, 256, 0, stream>>>(x, Wb, att, ei, edge_attr, xhb, si,
                                        sj, cnt, slots, N, E, G);
  gather_kernel<<<(N + 3) / 4, 256, 0, stream>>>(cnt, slots, si, sj, ce, xhb,
                                                 out, N);
}